// Round 2
// baseline (126.285 us; speedup 1.0000x reference)
//
#include <hip/hip_runtime.h>
#include <math.h>
#include <stdint.h>

#define NEGV -1e30f

constexpr int B_  = 16;
constexpr int CL  = 512;
constexpr int QL  = 64;
constexpr int H   = 768;
constexpr int OD  = 4 * H;     // 3072 output cols
constexpr int DC  = 128;       // d-chunk
constexpr int NCH = H / DC;    // 6
constexpr int RPB = 16;        // rows per block (4 waves x 4 rows)
constexpr int RPW = 4;         // rows per wave

// ws layout (floats)
constexpr size_t WS_QW     = 0;            // [1024]   qw[b,j] (incl b_q + b_cq)
constexpr size_t WS_ROWMAX = 1024;         // [8192]   max_j s (c_mask applied)
constexpr size_t WS_BATT   = 9216;         // [8192]   b_att
constexpr size_t WS_PART   = 17408;        // [16*32*768] q2c partials
constexpr size_t WS_Q2C    = 410624;       // [12288]  q2c[b,d]

__device__ __forceinline__ float rlane(float v, int l) {
  return __int_as_float(__builtin_amdgcn_readlane(__float_as_int(v), l));
}
__device__ __forceinline__ float wredmax(float v) {
#pragma unroll
  for (int off = 32; off; off >>= 1) v = fmaxf(v, __shfl_xor(v, off));
  return v;
}
__device__ __forceinline__ float wredsum(float v) {
#pragma unroll
  for (int off = 32; off; off >>= 1) v += __shfl_xor(v, off);
  return v;
}
__device__ __forceinline__ const float* uptr(const float* p) {
  unsigned long long v = (unsigned long long)(uintptr_t)p;
  unsigned lo = __builtin_amdgcn_readfirstlane((unsigned)v);
  unsigned hi = __builtin_amdgcn_readfirstlane((unsigned)(v >> 32));
  return (const float*)(uintptr_t)(((unsigned long long)hi << 32) | lo);
}

// ---------------- qw[b,j] = q[b,j,:] . w_q + b_q + b_cq ----------------
__global__ __launch_bounds__(256) void k_qw(const float* __restrict__ q,
                                            const float* __restrict__ w_q,
                                            const float* __restrict__ b_q,
                                            const float* __restrict__ b_cq,
                                            float* __restrict__ qw) {
  int w = threadIdx.x >> 6, lane = threadIdx.x & 63;
  int row = blockIdx.x * 4 + w;                 // 0..1023 = b*QL+j
  const float* qr = q + (size_t)row * H;
  float s = 0.f;
  for (int d = lane; d < H; d += 64) s += qr[d] * w_q[d];
#pragma unroll
  for (int off = 32; off; off >>= 1) s += __shfl_xor(s, off);
  if (lane == 0) qw[row] = s + b_q[0] + b_cq[0];
}

// ---------------- main kernel: s, softmax_j, c2q, out segs 0/1/2 ----------------
// wave-per-4-rows; lane = j. qS is the only big LDS buffer, reused by both phases.
__global__ __launch_bounds__(256, 2) void ka(const float* __restrict__ c,
                                             const float* __restrict__ q,
                                             const float* __restrict__ c_mask,
                                             const float* __restrict__ q_mask,
                                             const float* __restrict__ w_c,
                                             const float* __restrict__ b_c,
                                             const float* __restrict__ w_cq,
                                             const float* __restrict__ qw,
                                             float* __restrict__ rowmax,
                                             float* __restrict__ out) {
  __shared__ float qS[QL * DC];   // [j][k4-swizzled], 32 KB

  const int t    = threadIdx.x;
  const int lane = t & 63;
  const int wid  = __builtin_amdgcn_readfirstlane(t >> 6);
  const int bb   = blockIdx.y;
  const int rowbase = blockIdx.x * RPB + wid * RPW;

  const float qw_r = qw[bb * QL + lane];        // includes b_q + b_cq
  const float qm_r = q_mask[bb * QL + lane];
  const float bc   = b_c[0];

  const size_t qbase = (size_t)bb * QL * H;
  const size_t crow0 = ((size_t)bb * CL + rowbase) * H;

  float sacc[RPW] = {0.f, 0.f, 0.f, 0.f};

  // ---- phase 1: s' = (c*w_cq) @ q^T  (cw excluded; row-const cancels in softmax)
  for (int ch = 0; ch < NCH; ++ch) {
    const int d0 = ch * DC;
    __syncthreads();
#pragma unroll
    for (int s2 = 0; s2 < 8; ++s2) {            // stage q' = q * w_cq (swizzled)
      int idx = t + s2 * 256;
      int j = idx >> 5, k4 = idx & 31;
      float4 v = *(const float4*)(q + qbase + (size_t)j * H + d0 + k4 * 4);
      float4 w = *(const float4*)(w_cq + d0 + k4 * 4);
      v.x *= w.x; v.y *= w.y; v.z *= w.z; v.w *= w.w;
      *(float4*)&qS[j * DC + (((k4 ^ j) & 31) << 2)] = v;
    }
    __syncthreads();
    const float* cp0 = uptr(c + crow0 + 0 * H + d0);
    const float* cp1 = uptr(c + crow0 + 1 * H + d0);
    const float* cp2 = uptr(c + crow0 + 2 * H + d0);
    const float* cp3 = uptr(c + crow0 + 3 * H + d0);
#pragma unroll 8
    for (int k4 = 0; k4 < 32; ++k4) {
      float4 q4 = *(const float4*)&qS[lane * DC + (((k4 ^ lane) & 31) << 2)];
      float4 c0 = *(const float4*)(cp0 + k4 * 4);
      float4 c1 = *(const float4*)(cp1 + k4 * 4);
      float4 c2 = *(const float4*)(cp2 + k4 * 4);
      float4 c3 = *(const float4*)(cp3 + k4 * 4);
      sacc[0] = fmaf(c0.x, q4.x, fmaf(c0.y, q4.y, fmaf(c0.z, q4.z, fmaf(c0.w, q4.w, sacc[0]))));
      sacc[1] = fmaf(c1.x, q4.x, fmaf(c1.y, q4.y, fmaf(c1.z, q4.z, fmaf(c1.w, q4.w, sacc[1]))));
      sacc[2] = fmaf(c2.x, q4.x, fmaf(c2.y, q4.y, fmaf(c2.z, q4.z, fmaf(c2.w, q4.w, sacc[2]))));
      sacc[3] = fmaf(c3.x, q4.x, fmaf(c3.y, q4.y, fmaf(c3.z, q4.z, fmaf(c3.w, q4.w, sacc[3]))));
    }
  }

  // ---- cw[r] = c[row,:] . w_c + b_c (needed only for rowmax)
  float cw[RPW];
#pragma unroll
  for (int r = 0; r < RPW; ++r) {
    float cwp = 0.f;
#pragma unroll
    for (int p = 0; p < 3; ++p) {
      int k = p * 256 + lane * 4;
      float4 c4 = *(const float4*)(c + crow0 + (size_t)r * H + k);
      float4 w4 = *(const float4*)(w_c + k);
      cwp += c4.x * w4.x + c4.y * w4.y + c4.z * w4.z + c4.w * w4.w;
    }
    cw[r] = wredsum(cwp) + bc;
  }

  // ---- phase 2: softmax over j (in-register, lane = j) + rowmax
  float a[RPW];
#pragma unroll
  for (int r = 0; r < RPW; ++r) {
    float s = sacc[r] + qw_r;
    float mraw = wredmax(s);                       // raw max (q_mask NOT applied)
    float sm = (qm_r > 0.5f) ? s : NEGV;
    float mm = wredmax(sm);
    float p  = __expf(sm - mm);
    float ps = wredsum(p);
    a[r] = p / ps;
    if (lane == 0) {
      float cmv = c_mask[bb * CL + rowbase + r];
      rowmax[bb * CL + rowbase + r] = (cmv > 0.5f) ? (mraw + cw[r]) : NEGV;
    }
  }

  // ---- phase 3: c2q = a @ q, write segs 0/1/2
  const int half = lane >> 5, l5 = lane & 31;
  for (int ch = 0; ch < NCH; ++ch) {
    const int d0 = ch * DC;
    __syncthreads();
#pragma unroll
    for (int s2 = 0; s2 < 8; ++s2) {              // stage raw q chunk (swizzled)
      int idx = t + s2 * 256;
      int j = idx >> 5, k4 = idx & 31;
      float4 v = *(const float4*)(q + qbase + (size_t)j * H + d0 + k4 * 4);
      *(float4*)&qS[j * DC + (((k4 ^ j) & 31) << 2)] = v;
    }
    __syncthreads();
    float o[4][4] = {};
#pragma unroll 4
    for (int jp = 0; jp < 32; ++jp) {
      int jj = jp + (lane & 32);                  // halves take j and j+32
      float4 q4 = *(const float4*)&qS[jj * DC + (((l5 ^ jp) & 31) << 2)];
#pragma unroll
      for (int r = 0; r < 4; ++r) {
        float a0 = rlane(a[r], jp);
        float a1 = rlane(a[r], jp + 32);
        float aj = (half == 0) ? a0 : a1;
        o[r][0] = fmaf(aj, q4.x, o[r][0]);
        o[r][1] = fmaf(aj, q4.y, o[r][1]);
        o[r][2] = fmaf(aj, q4.z, o[r][2]);
        o[r][3] = fmaf(aj, q4.w, o[r][3]);
      }
    }
#pragma unroll
    for (int r = 0; r < 4; ++r)
#pragma unroll
      for (int e = 0; e < 4; ++e) o[r][e] += __shfl_xor(o[r][e], 32);
#pragma unroll
    for (int r2 = 0; r2 < 2; ++r2) {
      float4 ov;
      if (half == 0) ov = make_float4(o[r2][0], o[r2][1], o[r2][2], o[r2][3]);
      else           ov = make_float4(o[r2 + 2][0], o[r2 + 2][1], o[r2 + 2][2], o[r2 + 2][3]);
      int rw = r2 + half * 2;
      size_t row = (size_t)bb * CL + rowbase + rw;
      float4 cv = *(const float4*)(c + row * H + d0 + l5 * 4);
      float* ob = out + row * OD + d0 + l5 * 4;
      *(float4*)(ob)         = cv;
      *(float4*)(ob + H)     = ov;
      *(float4*)(ob + 2 * H) = make_float4(cv.x * ov.x, cv.y * ov.y,
                                           cv.z * ov.z, cv.w * ov.w);
    }
  }
}

// ---------------- b_att = softmax_i(rowmax) ----------------
__global__ __launch_bounds__(256) void kb1(const float* __restrict__ rowmax,
                                           float* __restrict__ batt) {
  int b = blockIdx.x, t = threadIdx.x;
  __shared__ float red[4];
  float v0 = rowmax[b * CL + t], v1 = rowmax[b * CL + t + 256];
  float m = fmaxf(v0, v1);
#pragma unroll
  for (int off = 32; off; off >>= 1) m = fmaxf(m, __shfl_xor(m, off));
  if ((t & 63) == 0) red[t >> 6] = m;
  __syncthreads();
  m = fmaxf(fmaxf(red[0], red[1]), fmaxf(red[2], red[3]));
  float p0 = __expf(v0 - m), p1 = __expf(v1 - m);
  float s = p0 + p1;
#pragma unroll
  for (int off = 32; off; off >>= 1) s += __shfl_xor(s, off);
  __syncthreads();
  if ((t & 63) == 0) red[t >> 6] = s;
  __syncthreads();
  s = red[0] + red[1] + red[2] + red[3];
  float inv = 1.0f / s;
  batt[b * CL + t] = p0 * inv;
  batt[b * CL + t + 256] = p1 * inv;
}

// ---------------- q2c partials: 32 splits of 16 rows each ----------------
__global__ __launch_bounds__(256) void kb2(const float* __restrict__ c,
                                           const float* __restrict__ batt,
                                           float* __restrict__ part) {
  int s = blockIdx.x, b = blockIdx.y, t = threadIdx.x;
  __shared__ float ba[16];
  if (t < 16) ba[t] = batt[b * CL + s * 16 + t];
  __syncthreads();
  const float* cb = c + ((size_t)b * CL + s * 16) * H;
  float a0 = 0.f, a1 = 0.f, a2 = 0.f;
  for (int r = 0; r < 16; ++r) {
    float w = ba[r];
    const float* cr = cb + (size_t)r * H;
    a0 += w * cr[t]; a1 += w * cr[t + 256]; a2 += w * cr[t + 512];
  }
  float* pr = part + ((size_t)b * 32 + s) * H;
  pr[t] = a0; pr[t + 256] = a1; pr[t + 512] = a2;
}

// ---------------- q2c reduce ----------------
__global__ __launch_bounds__(256) void kb3(const float* __restrict__ part,
                                           float* __restrict__ q2c) {
  int b = blockIdx.x / 3, third = blockIdx.x % 3, t = threadIdx.x;
  int d = third * 256 + t;
  float s = 0.f;
  for (int k = 0; k < 32; ++k) s += part[((size_t)b * 32 + k) * H + d];
  q2c[b * H + d] = s;
}

// ---------------- out seg3 = c * q2c ----------------
__global__ __launch_bounds__(256) void kc(const float* __restrict__ c,
                                          const float* __restrict__ q2c,
                                          float* __restrict__ out) {
  const float4* c4 = (const float4*)c;
  const float4* g4 = (const float4*)q2c;
  float4* o4 = (float4*)out;
  int idx = blockIdx.x * 256 + threadIdx.x;
#pragma unroll
  for (int k = 0; k < 3; ++k, idx += 2048 * 256) {
    int row = idx / 192, dq = idx - row * 192;   // row = b*CL+i, dq = d/4
    int b = row >> 9;
    float4 cv = c4[(size_t)row * 192 + dq];
    float4 gv = g4[b * 192 + dq];
    float4 r;
    r.x = cv.x * gv.x; r.y = cv.y * gv.y; r.z = cv.z * gv.z; r.w = cv.w * gv.w;
    o4[(size_t)row * 768 + 576 + dq] = r;
  }
}

extern "C" void kernel_launch(void* const* d_in, const int* in_sizes, int n_in,
                              void* d_out, int out_size, void* d_ws, size_t ws_size,
                              hipStream_t stream) {
  const float* c      = (const float*)d_in[0];
  const float* q      = (const float*)d_in[1];
  const float* c_mask = (const float*)d_in[2];
  const float* q_mask = (const float*)d_in[3];
  const float* w_c    = (const float*)d_in[4];
  const float* b_c    = (const float*)d_in[5];
  const float* w_q    = (const float*)d_in[6];
  const float* b_q    = (const float*)d_in[7];
  const float* w_cq   = (const float*)d_in[8];
  const float* b_cq   = (const float*)d_in[9];
  float* out = (float*)d_out;
  float* ws  = (float*)d_ws;
  float* qw     = ws + WS_QW;
  float* rowmax = ws + WS_ROWMAX;
  float* batt   = ws + WS_BATT;
  float* part   = ws + WS_PART;
  float* q2c    = ws + WS_Q2C;

  k_qw<<<256, 256, 0, stream>>>(q, w_q, b_q, b_cq, qw);
  ka<<<dim3(CL / RPB, B_), 256, 0, stream>>>(c, q, c_mask, q_mask, w_c, b_c,
                                             w_cq, qw, rowmax, out);
  kb1<<<B_, 256, 0, stream>>>(rowmax, batt);
  kb2<<<dim3(32, B_), 256, 0, stream>>>(c, batt, part);
  kb3<<<B_ * 3, 256, 0, stream>>>(part, q2c);
  kc<<<2048, 256, 0, stream>>>(c, q2c, out);
}

// Round 3
// 65.358 us; speedup vs baseline: 1.9322x; 1.9322x over previous
//
#include <hip/hip_runtime.h>
#include <math.h>
#include <stdint.h>

#define NEGV -1e30f
typedef unsigned short u16;
typedef unsigned int u32;
typedef short bfx8 __attribute__((ext_vector_type(8)));
typedef float f32x4 __attribute__((ext_vector_type(4)));

constexpr int B_  = 16;
constexpr int CL  = 512;
constexpr int QL  = 64;
constexpr int H   = 768;
constexpr int OD  = 4 * H;     // 3072 output cols
constexpr int IT  = 16;        // i-rows per block in ka

// ws layout (float offsets)
constexpr size_t WS_QW     = 0;            // [1024]   qw[b,j] (incl b_q + b_cq)
constexpr size_t WS_ROWMAX = 1024;         // [8192]
constexpr size_t WS_BATT   = 9216;         // [8192]
constexpr size_t WS_PART   = 17408;        // [16*32*768]
constexpr size_t WS_Q2C    = 410624;       // [12288]
constexpr size_t WS_QB     = 422912;       // u16[16*64*768]  bf16(q*w_cq) [b][j][d]
constexpr size_t WS_QT     = 816128;       // u16[16*768*64]  bf16(q)^T    [b][d][j]

__device__ __forceinline__ u16 f2b(float x) {     // fp32 -> bf16 RTNE
  u32 u = __float_as_uint(x);
  u += 0x7FFFu + ((u >> 16) & 1u);
  return (u16)(u >> 16);
}
__device__ __forceinline__ float wredmax(float v) {
#pragma unroll
  for (int off = 32; off; off >>= 1) v = fmaxf(v, __shfl_xor(v, off));
  return v;
}
__device__ __forceinline__ float wredsum(float v) {
#pragma unroll
  for (int off = 32; off; off >>= 1) v += __shfl_xor(v, off);
  return v;
}

// ---------------- qw[b,j] = q[b,j,:] . w_q + b_q + b_cq ----------------
__global__ __launch_bounds__(256) void k_qw(const float* __restrict__ q,
                                            const float* __restrict__ w_q,
                                            const float* __restrict__ b_q,
                                            const float* __restrict__ b_cq,
                                            float* __restrict__ qw) {
  int w = threadIdx.x >> 6, lane = threadIdx.x & 63;
  int row = blockIdx.x * 4 + w;
  const float* qr = q + (size_t)row * H;
  float s = 0.f;
  for (int d = lane; d < H; d += 64) s += qr[d] * w_q[d];
#pragma unroll
  for (int off = 32; off; off >>= 1) s += __shfl_xor(s, off);
  if (lane == 0) qw[row] = s + b_q[0] + b_cq[0];
}

// ---------------- build qb = bf16(q*w_cq) [b][j][d], qT = bf16(q)^T [b][d][j] ----------------
__global__ __launch_bounds__(256) void k_qprep(const float* __restrict__ q,
                                               const float* __restrict__ w_cq,
                                               u16* __restrict__ qb,
                                               u16* __restrict__ qT) {
  __shared__ u16 tile[64 * 132];
  const int ch = blockIdx.x, bb = blockIdx.y, t = threadIdx.x;
  const int d0 = ch * 128;
#pragma unroll
  for (int s = 0; s < 8; ++s) {
    int idx = t + s * 256;
    int j = idx >> 5, d4 = idx & 31;
    size_t go = ((size_t)(bb * QL + j)) * H + d0 + d4 * 4;
    float4 v = *(const float4*)(q + go);
    float4 w = *(const float4*)(w_cq + d0 + d4 * 4);
    uint2 raw, scl;
    raw.x = f2b(v.x) | ((u32)f2b(v.y) << 16);
    raw.y = f2b(v.z) | ((u32)f2b(v.w) << 16);
    scl.x = f2b(v.x * w.x) | ((u32)f2b(v.y * w.y) << 16);
    scl.y = f2b(v.z * w.z) | ((u32)f2b(v.w * w.w) << 16);
    *(uint2*)(qb + go) = scl;
    *(uint2*)&tile[j * 132 + d4 * 4] = raw;
  }
  __syncthreads();
  const int dr = t >> 1, half = t & 1;
#pragma unroll
  for (int g = 0; g < 4; ++g) {
    u16 tmp[8];
#pragma unroll
    for (int e = 0; e < 8; ++e) tmp[e] = tile[(half * 32 + g * 8 + e) * 132 + dr];
    uint4 o;
    o.x = tmp[0] | ((u32)tmp[1] << 16); o.y = tmp[2] | ((u32)tmp[3] << 16);
    o.z = tmp[4] | ((u32)tmp[5] << 16); o.w = tmp[6] | ((u32)tmp[7] << 16);
    *(uint4*)(qT + ((size_t)bb * H + d0 + dr) * QL + half * 32 + g * 8) = o;
  }
}

// ---------------- main kernel: MFMA s, softmax_j, MFMA c2q, out segs 0/1/2 ----------------
__global__ __launch_bounds__(256, 2) void ka(const float* __restrict__ c,
                                             const float* __restrict__ c_mask,
                                             const float* __restrict__ q_mask,
                                             const float* __restrict__ w_c,
                                             const float* __restrict__ b_c,
                                             const float* __restrict__ qw,
                                             const u16* __restrict__ qb,
                                             const u16* __restrict__ qT,
                                             float* __restrict__ rowmax,
                                             float* __restrict__ out) {
  __shared__ u16 cA[IT * H];       // bf16 c tile, XOR-swizzled, 24 KB
  __shared__ float sS[IT * 68];    // s tile f32
  __shared__ u16 aS[IT * 64];      // a tile bf16, XOR-swizzled

  const int t = threadIdx.x, lane = t & 63;
  const int wid = __builtin_amdgcn_readfirstlane(t >> 6);
  const int bb = blockIdx.y, i0 = blockIdx.x * IT;
  const int lr = lane & 15, lg = lane >> 4;
  const int sw = (lr & 7) << 4;

  // ---- stage A: c tile (16 x 768) -> bf16 swizzled LDS
  {
    int row = t >> 4, c4b = t & 15;
    size_t cb0 = ((size_t)bb * CL + i0 + row) * H;
#pragma unroll
    for (int u = 0; u < 12; ++u) {
      int col4 = c4b + u * 16;
      float4 v = *(const float4*)(c + cb0 + col4 * 4);
      uint2 pk;
      pk.x = f2b(v.x) | ((u32)f2b(v.y) << 16);
      pk.y = f2b(v.z) | ((u32)f2b(v.w) << 16);
      int byte = row * 1536 + ((col4 * 8) ^ ((row & 7) << 4));
      *(uint2*)((char*)cA + byte) = pk;
    }
  }
  const float qw_r = qw[bb * QL + lane];       // includes b_q + b_cq
  const float qm_r = q_mask[bb * QL + lane];
  __syncthreads();

  // ---- phase 1: s' = c @ (q*w_cq)^T  for col-group wid (16 j-cols)
  f32x4 acc0 = {0.f, 0.f, 0.f, 0.f}, acc1 = {0.f, 0.f, 0.f, 0.f};
  {
    const u16* qbp = qb + ((size_t)bb * QL + wid * 16 + lr) * H + lg * 8;
    const char* ap = (const char*)cA + lr * 1536;
#pragma unroll
    for (int k0 = 0; k0 < 768; k0 += 64) {
      bfx8 av0 = *(const bfx8*)(ap + ((k0 * 2 + lg * 16) ^ sw));
      bfx8 bv0 = *(const bfx8*)(qbp + k0);
      bfx8 av1 = *(const bfx8*)(ap + (((k0 + 32) * 2 + lg * 16) ^ sw));
      bfx8 bv1 = *(const bfx8*)(qbp + k0 + 32);
      acc0 = __builtin_amdgcn_mfma_f32_16x16x32_bf16(av0, bv0, acc0, 0, 0, 0);
      acc1 = __builtin_amdgcn_mfma_f32_16x16x32_bf16(av1, bv1, acc1, 0, 0, 0);
    }
  }
#pragma unroll
  for (int m = 0; m < 4; ++m)
    sS[(lg * 4 + m) * 68 + wid * 16 + lr] = acc0[m] + acc1[m];

  // ---- cw for this wave's 4 softmax rows (fp32, from global; feeds rowmax only)
  float cwv[4];
#pragma unroll
  for (int rr = 0; rr < 4; ++rr) {
    size_t ro = ((size_t)bb * CL + i0 + wid * 4 + rr) * H;
    float p = 0.f;
#pragma unroll
    for (int pi = 0; pi < 3; ++pi) {
      int k = pi * 256 + lane * 4;
      float4 cv = *(const float4*)(c + ro + k);
      float4 wv = *(const float4*)(w_c + k);
      p += cv.x * wv.x + cv.y * wv.y + cv.z * wv.z + cv.w * wv.w;
    }
    cwv[rr] = wredsum(p);
  }
  const float bc = b_c[0];
  __syncthreads();

  // ---- phase 2: softmax over j (lane = j), rowmax, a -> bf16 LDS
#pragma unroll
  for (int rr = 0; rr < 4; ++rr) {
    int r = wid * 4 + rr;
    float s = sS[r * 68 + lane] + qw_r;
    float mraw = wredmax(s);
    float sm = (qm_r > 0.5f) ? s : NEGV;
    float mm = wredmax(sm);
    float p = __expf(sm - mm);
    float ps = wredsum(p);
    float a = p / ps;
    if (lane == 0) {
      float cmv = c_mask[bb * CL + i0 + r];
      rowmax[bb * CL + i0 + r] = (cmv > 0.5f) ? (mraw + cwv[rr] + bc) : NEGV;
    }
    int byte = r * 128 + ((lane * 2) ^ ((r & 7) << 4));
    *(u16*)((char*)aS + byte) = f2b(a);
  }
  __syncthreads();

  // ---- phase 3: c2q = a @ q  (A from aS, B from qT), write segs 0/1/2
  bfx8 a0 = *(const bfx8*)((char*)aS + lr * 128 + ((lg * 16) ^ sw));
  bfx8 a1 = *(const bfx8*)((char*)aS + lr * 128 + ((64 + lg * 16) ^ sw));
  const u16* qTp = qT + (size_t)bb * H * QL;
  f32x4 o[12];
#pragma unroll
  for (int u = 0; u < 12; ++u) {
    int dR = (wid * 12 + u) * 16 + lr;
    bfx8 b0 = *(const bfx8*)(qTp + (size_t)dR * QL + lg * 8);
    bfx8 b1 = *(const bfx8*)(qTp + (size_t)dR * QL + 32 + lg * 8);
    f32x4 v = {0.f, 0.f, 0.f, 0.f};
    v = __builtin_amdgcn_mfma_f32_16x16x32_bf16(a0, b0, v, 0, 0, 0);
    v = __builtin_amdgcn_mfma_f32_16x16x32_bf16(a1, b1, v, 0, 0, 0);
    o[u] = v;
  }
#pragma unroll
  for (int u = 0; u < 12; ++u) {
    int d = (wid * 12 + u) * 16 + lr;
#pragma unroll
    for (int m = 0; m < 4; ++m) {
      size_t row = (size_t)bb * CL + i0 + lg * 4 + m;
      float cv = c[row * H + d];
      float ov = o[u][m];
      float* ob = out + row * OD;
      ob[d] = cv;
      ob[H + d] = ov;
      ob[2 * H + d] = cv * ov;
    }
  }
}

// ---------------- b_att = softmax_i(rowmax) ----------------
__global__ __launch_bounds__(256) void kb1(const float* __restrict__ rowmax,
                                           float* __restrict__ batt) {
  int b = blockIdx.x, t = threadIdx.x;
  __shared__ float red[4];
  float v0 = rowmax[b * CL + t], v1 = rowmax[b * CL + t + 256];
  float m = fmaxf(v0, v1);
#pragma unroll
  for (int off = 32; off; off >>= 1) m = fmaxf(m, __shfl_xor(m, off));
  if ((t & 63) == 0) red[t >> 6] = m;
  __syncthreads();
  m = fmaxf(fmaxf(red[0], red[1]), fmaxf(red[2], red[3]));
  float p0 = __expf(v0 - m), p1 = __expf(v1 - m);
  float s = p0 + p1;
#pragma unroll
  for (int off = 32; off; off >>= 1) s += __shfl_xor(s, off);
  __syncthreads();
  if ((t & 63) == 0) red[t >> 6] = s;
  __syncthreads();
  s = red[0] + red[1] + red[2] + red[3];
  float inv = 1.0f / s;
  batt[b * CL + t] = p0 * inv;
  batt[b * CL + t + 256] = p1 * inv;
}

// ---------------- q2c partials ----------------
__global__ __launch_bounds__(256) void kb2(const float* __restrict__ c,
                                           const float* __restrict__ batt,
                                           float* __restrict__ part) {
  int s = blockIdx.x, b = blockIdx.y, t = threadIdx.x;
  __shared__ float ba[16];
  if (t < 16) ba[t] = batt[b * CL + s * 16 + t];
  __syncthreads();
  const float* cb = c + ((size_t)b * CL + s * 16) * H;
  float a0 = 0.f, a1 = 0.f, a2 = 0.f;
  for (int r = 0; r < 16; ++r) {
    float w = ba[r];
    const float* cr = cb + (size_t)r * H;
    a0 += w * cr[t]; a1 += w * cr[t + 256]; a2 += w * cr[t + 512];
  }
  float* pr = part + ((size_t)b * 32 + s) * H;
  pr[t] = a0; pr[t + 256] = a1; pr[t + 512] = a2;
}

// ---------------- q2c reduce ----------------
__global__ __launch_bounds__(256) void kb3(const float* __restrict__ part,
                                           float* __restrict__ q2c) {
  int b = blockIdx.x / 3, third = blockIdx.x % 3, t = threadIdx.x;
  int d = third * 256 + t;
  float s = 0.f;
  for (int k = 0; k < 32; ++k) s += part[((size_t)b * 32 + k) * H + d];
  q2c[b * H + d] = s;
}

// ---------------- out seg3 = c * q2c ----------------
__global__ __launch_bounds__(256) void kc(const float* __restrict__ c,
                                          const float* __restrict__ q2c,
                                          float* __restrict__ out) {
  const float4* c4 = (const float4*)c;
  const float4* g4 = (const float4*)q2c;
  float4* o4 = (float4*)out;
  int idx = blockIdx.x * 256 + threadIdx.x;
#pragma unroll
  for (int k = 0; k < 3; ++k, idx += 2048 * 256) {
    int row = idx / 192, dq = idx - row * 192;
    int b = row >> 9;
    float4 cv = c4[(size_t)row * 192 + dq];
    float4 gv = g4[b * 192 + dq];
    float4 r;
    r.x = cv.x * gv.x; r.y = cv.y * gv.y; r.z = cv.z * gv.z; r.w = cv.w * gv.w;
    o4[(size_t)row * 768 + 576 + dq] = r;
  }
}

extern "C" void kernel_launch(void* const* d_in, const int* in_sizes, int n_in,
                              void* d_out, int out_size, void* d_ws, size_t ws_size,
                              hipStream_t stream) {
  const float* c      = (const float*)d_in[0];
  const float* q      = (const float*)d_in[1];
  const float* c_mask = (const float*)d_in[2];
  const float* q_mask = (const float*)d_in[3];
  const float* w_c    = (const float*)d_in[4];
  const float* b_c    = (const float*)d_in[5];
  const float* w_q    = (const float*)d_in[6];
  const float* b_q    = (const float*)d_in[7];
  const float* w_cq   = (const float*)d_in[8];
  const float* b_cq   = (const float*)d_in[9];
  float* out = (float*)d_out;
  float* ws  = (float*)d_ws;
  float* qw     = ws + WS_QW;
  float* rowmax = ws + WS_ROWMAX;
  float* batt   = ws + WS_BATT;
  float* part   = ws + WS_PART;
  float* q2c    = ws + WS_Q2C;
  u16*   qb     = (u16*)(ws + WS_QB);
  u16*   qT     = (u16*)(ws + WS_QT);

  k_qw<<<256, 256, 0, stream>>>(q, w_q, b_q, b_cq, qw);
  k_qprep<<<dim3(6, B_), 256, 0, stream>>>(q, w_cq, qb, qT);
  ka<<<dim3(CL / IT, B_), 256, 0, stream>>>(c, c_mask, q_mask, w_c, b_c,
                                            qw, qb, qT, rowmax, out);
  kb1<<<B_, 256, 0, stream>>>(rowmax, batt);
  kb2<<<dim3(32, B_), 256, 0, stream>>>(c, batt, part);
  kb3<<<B_ * 3, 256, 0, stream>>>(part, q2c);
  kc<<<2048, 256, 0, stream>>>(c, q2c, out);
}

// Round 4
// 64.632 us; speedup vs baseline: 1.9539x; 1.0112x over previous
//
#include <hip/hip_runtime.h>
#include <math.h>
#include <stdint.h>

#define NEGV -1e30f
typedef unsigned short u16;
typedef unsigned int u32;
typedef short bfx8 __attribute__((ext_vector_type(8)));
typedef float f32x4 __attribute__((ext_vector_type(4)));

constexpr int B_  = 16;
constexpr int CL  = 512;
constexpr int QL  = 64;
constexpr int H   = 768;
constexpr int OD  = 4 * H;     // 3072 output cols
constexpr int IT  = 16;        // i-rows per block in ka
constexpr int OSTR = 772;      // oS row stride (pad: 4*772 % 32 = 16 -> 2-way only)

// ws layout (float offsets)
constexpr size_t WS_QW     = 0;            // [1024]   qw[b,j] (incl b_q + b_cq)
constexpr size_t WS_ROWMAX = 1024;         // [8192]
constexpr size_t WS_BATT   = 9216;         // [8192]
constexpr size_t WS_PART   = 17408;        // [16*32*768]
constexpr size_t WS_Q2C    = 410624;       // [12288]
constexpr size_t WS_QB     = 422912;       // u16[16*64*768]  bf16(q*w_cq) [b][j][d]
constexpr size_t WS_QT     = 816128;       // u16[16*768*64]  bf16(q)^T    [b][d][j]

__device__ __forceinline__ u16 f2b(float x) {     // fp32 -> bf16 RTNE
  u32 u = __float_as_uint(x);
  u += 0x7FFFu + ((u >> 16) & 1u);
  return (u16)(u >> 16);
}
__device__ __forceinline__ float wredmax(float v) {
#pragma unroll
  for (int off = 32; off; off >>= 1) v = fmaxf(v, __shfl_xor(v, off));
  return v;
}
__device__ __forceinline__ float wredsum(float v) {
#pragma unroll
  for (int off = 32; off; off >>= 1) v += __shfl_xor(v, off);
  return v;
}

// ---------------- qw[b,j] = q[b,j,:] . w_q + b_q + b_cq ----------------
__global__ __launch_bounds__(256) void k_qw(const float* __restrict__ q,
                                            const float* __restrict__ w_q,
                                            const float* __restrict__ b_q,
                                            const float* __restrict__ b_cq,
                                            float* __restrict__ qw) {
  int w = threadIdx.x >> 6, lane = threadIdx.x & 63;
  int row = blockIdx.x * 4 + w;
  const float* qr = q + (size_t)row * H;
  float s = 0.f;
  for (int d = lane; d < H; d += 64) s += qr[d] * w_q[d];
#pragma unroll
  for (int off = 32; off; off >>= 1) s += __shfl_xor(s, off);
  if (lane == 0) qw[row] = s + b_q[0] + b_cq[0];
}

// ---------------- build qb = bf16(q*w_cq) [b][j][d], qT = bf16(q)^T [b][d][j] ----------------
__global__ __launch_bounds__(256) void k_qprep(const float* __restrict__ q,
                                               const float* __restrict__ w_cq,
                                               u16* __restrict__ qb,
                                               u16* __restrict__ qT) {
  __shared__ u16 tile[64 * 132];
  const int ch = blockIdx.x, bb = blockIdx.y, t = threadIdx.x;
  const int d0 = ch * 128;
#pragma unroll
  for (int s = 0; s < 8; ++s) {
    int idx = t + s * 256;
    int j = idx >> 5, d4 = idx & 31;
    size_t go = ((size_t)(bb * QL + j)) * H + d0 + d4 * 4;
    float4 v = *(const float4*)(q + go);
    float4 w = *(const float4*)(w_cq + d0 + d4 * 4);
    uint2 raw, scl;
    raw.x = f2b(v.x) | ((u32)f2b(v.y) << 16);
    raw.y = f2b(v.z) | ((u32)f2b(v.w) << 16);
    scl.x = f2b(v.x * w.x) | ((u32)f2b(v.y * w.y) << 16);
    scl.y = f2b(v.z * w.z) | ((u32)f2b(v.w * w.w) << 16);
    *(uint2*)(qb + go) = scl;
    *(uint2*)&tile[j * 132 + d4 * 4] = raw;
  }
  __syncthreads();
  const int dr = t >> 1, half = t & 1;
#pragma unroll
  for (int g = 0; g < 4; ++g) {
    u16 tmp[8];
#pragma unroll
    for (int e = 0; e < 8; ++e) tmp[e] = tile[(half * 32 + g * 8 + e) * 132 + dr];
    uint4 o;
    o.x = tmp[0] | ((u32)tmp[1] << 16); o.y = tmp[2] | ((u32)tmp[3] << 16);
    o.z = tmp[4] | ((u32)tmp[5] << 16); o.w = tmp[6] | ((u32)tmp[7] << 16);
    *(uint4*)(qT + ((size_t)bb * H + d0 + dr) * QL + half * 32 + g * 8) = o;
  }
}

// ---------------- main kernel: MFMA s, softmax_j, MFMA c2q, out segs 0/1/2 ----------------
__global__ __launch_bounds__(256, 2) void ka(const float* __restrict__ c,
                                             const float* __restrict__ c_mask,
                                             const float* __restrict__ q_mask,
                                             const float* __restrict__ w_c,
                                             const float* __restrict__ b_c,
                                             const float* __restrict__ qw,
                                             const u16* __restrict__ qb,
                                             const u16* __restrict__ qT,
                                             float* __restrict__ rowmax,
                                             float* __restrict__ out) {
  // union: phase 1 uses first 24 KB as bf16 cA tile; epilogue uses all as f32 oS
  __shared__ __align__(16) char shm[IT * OSTR * 4];  // 49.4 KB
  __shared__ float sS[IT * 68];
  __shared__ u16 aS[IT * 64];
  u16* cA = (u16*)shm;
  float* oS = (float*)shm;

  const int t = threadIdx.x, lane = t & 63;
  const int wid = __builtin_amdgcn_readfirstlane(t >> 6);
  const int bb = blockIdx.y, i0 = blockIdx.x * IT;
  const int lr = lane & 15, lg = lane >> 4;
  const int sw = (lr & 7) << 4;

  // ---- stage A: c tile (16 x 768) -> bf16 swizzled LDS
  {
    int row = t >> 4, c4b = t & 15;
    size_t cb0 = ((size_t)bb * CL + i0 + row) * H;
#pragma unroll
    for (int u = 0; u < 12; ++u) {
      int col4 = c4b + u * 16;
      float4 v = *(const float4*)(c + cb0 + col4 * 4);
      uint2 pk;
      pk.x = f2b(v.x) | ((u32)f2b(v.y) << 16);
      pk.y = f2b(v.z) | ((u32)f2b(v.w) << 16);
      int byte = row * 1536 + ((col4 * 8) ^ ((row & 7) << 4));
      *(uint2*)((char*)cA + byte) = pk;
    }
  }
  const float qw_r = qw[bb * QL + lane];       // includes b_q + b_cq
  const float qm_r = q_mask[bb * QL + lane];
  __syncthreads();

  // ---- phase 1: s' = c @ (q*w_cq)^T  for col-group wid (16 j-cols)
  f32x4 acc0 = {0.f, 0.f, 0.f, 0.f}, acc1 = {0.f, 0.f, 0.f, 0.f};
  {
    const u16* qbp = qb + ((size_t)bb * QL + wid * 16 + lr) * H + lg * 8;
    const char* ap = (const char*)cA + lr * 1536;
#pragma unroll
    for (int k0 = 0; k0 < 768; k0 += 64) {
      bfx8 av0 = *(const bfx8*)(ap + ((k0 * 2 + lg * 16) ^ sw));
      bfx8 bv0 = *(const bfx8*)(qbp + k0);
      bfx8 av1 = *(const bfx8*)(ap + (((k0 + 32) * 2 + lg * 16) ^ sw));
      bfx8 bv1 = *(const bfx8*)(qbp + k0 + 32);
      acc0 = __builtin_amdgcn_mfma_f32_16x16x32_bf16(av0, bv0, acc0, 0, 0, 0);
      acc1 = __builtin_amdgcn_mfma_f32_16x16x32_bf16(av1, bv1, acc1, 0, 0, 0);
    }
  }
#pragma unroll
  for (int m = 0; m < 4; ++m)
    sS[(lg * 4 + m) * 68 + wid * 16 + lr] = acc0[m] + acc1[m];

  // ---- cw for this wave's 4 softmax rows (fp32, from global; feeds rowmax only)
  float cwv[4];
#pragma unroll
  for (int rr = 0; rr < 4; ++rr) {
    size_t ro = ((size_t)bb * CL + i0 + wid * 4 + rr) * H;
    float p = 0.f;
#pragma unroll
    for (int pi = 0; pi < 3; ++pi) {
      int k = pi * 256 + lane * 4;
      float4 cv = *(const float4*)(c + ro + k);
      float4 wv = *(const float4*)(w_c + k);
      p += cv.x * wv.x + cv.y * wv.y + cv.z * wv.z + cv.w * wv.w;
    }
    cwv[rr] = wredsum(p);
  }
  const float bc = b_c[0];
  __syncthreads();

  // ---- phase 2: softmax over j (lane = j), rowmax, a -> bf16 LDS
#pragma unroll
  for (int rr = 0; rr < 4; ++rr) {
    int r = wid * 4 + rr;
    float s = sS[r * 68 + lane] + qw_r;
    float mraw = wredmax(s);
    float sm = (qm_r > 0.5f) ? s : NEGV;
    float mm = wredmax(sm);
    float p = __expf(sm - mm);
    float ps = wredsum(p);
    float a = p / ps;
    if (lane == 0) {
      float cmv = c_mask[bb * CL + i0 + r];
      rowmax[bb * CL + i0 + r] = (cmv > 0.5f) ? (mraw + cwv[rr] + bc) : NEGV;
    }
    int byte = r * 128 + ((lane * 2) ^ ((r & 7) << 4));
    *(u16*)((char*)aS + byte) = f2b(a);
  }
  __syncthreads();

  // ---- phase 3: c2q = a @ q  (A from aS, B from qT)
  bfx8 a0 = *(const bfx8*)((char*)aS + lr * 128 + ((lg * 16) ^ sw));
  bfx8 a1 = *(const bfx8*)((char*)aS + lr * 128 + ((64 + lg * 16) ^ sw));
  const u16* qTp = qT + (size_t)bb * H * QL;
  f32x4 o[12];
#pragma unroll
  for (int u = 0; u < 12; ++u) {
    int dR = (wid * 12 + u) * 16 + lr;
    bfx8 b0 = *(const bfx8*)(qTp + (size_t)dR * QL + lg * 8);
    bfx8 b1 = *(const bfx8*)(qTp + (size_t)dR * QL + 32 + lg * 8);
    f32x4 v = {0.f, 0.f, 0.f, 0.f};
    v = __builtin_amdgcn_mfma_f32_16x16x32_bf16(a0, b0, v, 0, 0, 0);
    v = __builtin_amdgcn_mfma_f32_16x16x32_bf16(a1, b1, v, 0, 0, 0);
    o[u] = v;
  }
  __syncthreads();   // cA no longer needed; shm becomes oS

  // ---- stage c2q into oS (2-way-max conflicts), then coalesced float4 epilogue
#pragma unroll
  for (int u = 0; u < 12; ++u) {
    int d = wid * 192 + u * 16 + lr;
#pragma unroll
    for (int m = 0; m < 4; ++m)
      oS[(lg * 4 + m) * OSTR + d] = o[u][m];
  }
  __syncthreads();
  {
    int row = t >> 4, c4b = t & 15;
    size_t grow = (size_t)bb * CL + i0 + row;
    const float* crow = c + grow * H;
    float* ob = out + grow * OD;
#pragma unroll
    for (int k = 0; k < 12; ++k) {
      int d = (c4b + k * 16) * 4;
      float4 cv = *(const float4*)(crow + d);
      float4 ov = *(const float4*)&oS[row * OSTR + d];
      *(float4*)(ob + d) = cv;
      *(float4*)(ob + H + d) = ov;
      *(float4*)(ob + 2 * H + d) = make_float4(cv.x * ov.x, cv.y * ov.y,
                                               cv.z * ov.z, cv.w * ov.w);
    }
  }
}

// ---------------- b_att = softmax_i(rowmax) ----------------
__global__ __launch_bounds__(256) void kb1(const float* __restrict__ rowmax,
                                           float* __restrict__ batt) {
  int b = blockIdx.x, t = threadIdx.x;
  __shared__ float red[4];
  float v0 = rowmax[b * CL + t], v1 = rowmax[b * CL + t + 256];
  float m = fmaxf(v0, v1);
#pragma unroll
  for (int off = 32; off; off >>= 1) m = fmaxf(m, __shfl_xor(m, off));
  if ((t & 63) == 0) red[t >> 6] = m;
  __syncthreads();
  m = fmaxf(fmaxf(red[0], red[1]), fmaxf(red[2], red[3]));
  float p0 = __expf(v0 - m), p1 = __expf(v1 - m);
  float s = p0 + p1;
#pragma unroll
  for (int off = 32; off; off >>= 1) s += __shfl_xor(s, off);
  __syncthreads();
  if ((t & 63) == 0) red[t >> 6] = s;
  __syncthreads();
  s = red[0] + red[1] + red[2] + red[3];
  float inv = 1.0f / s;
  batt[b * CL + t] = p0 * inv;
  batt[b * CL + t + 256] = p1 * inv;
}

// ---------------- q2c partials (float4) ----------------
__global__ __launch_bounds__(192) void kb2(const float* __restrict__ c,
                                           const float* __restrict__ batt,
                                           float* __restrict__ part) {
  int s = blockIdx.x, b = blockIdx.y, t = threadIdx.x;   // t < 192
  __shared__ float ba[16];
  if (t < 16) ba[t] = batt[b * CL + s * 16 + t];
  __syncthreads();
  const float* cb = c + ((size_t)b * CL + s * 16) * H;
  float4 acc = make_float4(0.f, 0.f, 0.f, 0.f);
#pragma unroll
  for (int r = 0; r < 16; ++r) {
    float w = ba[r];
    float4 cv = *(const float4*)(cb + (size_t)r * H + t * 4);
    acc.x += w * cv.x; acc.y += w * cv.y; acc.z += w * cv.z; acc.w += w * cv.w;
  }
  *(float4*)(part + ((size_t)b * 32 + s) * H + t * 4) = acc;
}

// ---------------- q2c reduce ----------------
__global__ __launch_bounds__(256) void kb3(const float* __restrict__ part,
                                           float* __restrict__ q2c) {
  int b = blockIdx.x / 3, third = blockIdx.x % 3, t = threadIdx.x;
  int d = third * 256 + t;
  float s = 0.f;
  for (int k = 0; k < 32; ++k) s += part[((size_t)b * 32 + k) * H + d];
  q2c[b * H + d] = s;
}

// ---------------- out seg3 = c * q2c ----------------
__global__ __launch_bounds__(256) void kc(const float* __restrict__ c,
                                          const float* __restrict__ q2c,
                                          float* __restrict__ out) {
  const float4* c4 = (const float4*)c;
  const float4* g4 = (const float4*)q2c;
  float4* o4 = (float4*)out;
  int idx = blockIdx.x * 256 + threadIdx.x;
#pragma unroll
  for (int k = 0; k < 3; ++k, idx += 2048 * 256) {
    int row = idx / 192, dq = idx - row * 192;
    int b = row >> 9;
    float4 cv = c4[(size_t)row * 192 + dq];
    float4 gv = g4[b * 192 + dq];
    float4 r;
    r.x = cv.x * gv.x; r.y = cv.y * gv.y; r.z = cv.z * gv.z; r.w = cv.w * gv.w;
    o4[(size_t)row * 768 + 576 + dq] = r;
  }
}

extern "C" void kernel_launch(void* const* d_in, const int* in_sizes, int n_in,
                              void* d_out, int out_size, void* d_ws, size_t ws_size,
                              hipStream_t stream) {
  const float* c      = (const float*)d_in[0];
  const float* q      = (const float*)d_in[1];
  const float* c_mask = (const float*)d_in[2];
  const float* q_mask = (const float*)d_in[3];
  const float* w_c    = (const float*)d_in[4];
  const float* b_c    = (const float*)d_in[5];
  const float* w_q    = (const float*)d_in[6];
  const float* b_q    = (const float*)d_in[7];
  const float* w_cq   = (const float*)d_in[8];
  const float* b_cq   = (const float*)d_in[9];
  float* out = (float*)d_out;
  float* ws  = (float*)d_ws;
  float* qw     = ws + WS_QW;
  float* rowmax = ws + WS_ROWMAX;
  float* batt   = ws + WS_BATT;
  float* part   = ws + WS_PART;
  float* q2c    = ws + WS_Q2C;
  u16*   qb     = (u16*)(ws + WS_QB);
  u16*   qT     = (u16*)(ws + WS_QT);

  k_qw<<<256, 256, 0, stream>>>(q, w_q, b_q, b_cq, qw);
  k_qprep<<<dim3(6, B_), 256, 0, stream>>>(q, w_cq, qb, qT);
  ka<<<dim3(CL / IT, B_), 256, 0, stream>>>(c, c_mask, q_mask, w_c, b_c,
                                            qw, qb, qT, rowmax, out);
  kb1<<<B_, 256, 0, stream>>>(rowmax, batt);
  kb2<<<dim3(32, B_), 192, 0, stream>>>(c, batt, part);
  kb3<<<B_ * 3, 256, 0, stream>>>(part, q2c);
  kc<<<2048, 256, 0, stream>>>(c, q2c, out);
}

// Round 5
// 61.132 us; speedup vs baseline: 2.0658x; 1.0572x over previous
//
#include <hip/hip_runtime.h>
#include <math.h>
#include <stdint.h>

#define NEGV -1e30f
typedef unsigned short u16;
typedef unsigned int u32;
typedef short bfx8 __attribute__((ext_vector_type(8)));
typedef float f32x4 __attribute__((ext_vector_type(4)));

constexpr int B_  = 16;
constexpr int CL  = 512;
constexpr int QL  = 64;
constexpr int H   = 768;
constexpr int OD  = 4 * H;     // 3072 output cols
constexpr int IT  = 16;        // i-rows per block in ka
constexpr int OSTR = 772;      // oS row stride in f32

// ws layout (float offsets)
constexpr size_t WS_QW     = 0;            // [1024]  qw[b,j] (incl b_q + b_cq)
constexpr size_t WS_ROWMAX = 1024;         // [8192]
constexpr size_t WS_PART   = 17408;        // [16*32*768]
constexpr size_t WS_Q2C    = 410624;       // [12288]
constexpr size_t WS_QBF    = 422912;       // u16[16][4][24][64][8]  frag-major bf16(q*w_cq)
constexpr size_t WS_QTF    = 816128;       // u16[16][48][2][64][8]  frag-major bf16(q)^T

__device__ __forceinline__ u16 f2b(float x) {     // fp32 -> bf16 RTNE
  u32 u = __float_as_uint(x);
  u += 0x7FFFu + ((u >> 16) & 1u);
  return (u16)(u >> 16);
}
__device__ __forceinline__ float wredmax(float v) {
#pragma unroll
  for (int off = 32; off; off >>= 1) v = fmaxf(v, __shfl_xor(v, off));
  return v;
}
__device__ __forceinline__ float wredsum(float v) {
#pragma unroll
  for (int off = 32; off; off >>= 1) v += __shfl_xor(v, off);
  return v;
}

// ---------------- prologue: qw + fragment-major qbF/qTF ----------------
// grid (7, B): ch<6 -> permute chunk d0=ch*128; ch==6 -> qw for the batch
__global__ __launch_bounds__(256) void k_qprep(const float* __restrict__ q,
                                               const float* __restrict__ w_cq,
                                               const float* __restrict__ w_q,
                                               const float* __restrict__ b_q,
                                               const float* __restrict__ b_cq,
                                               u16* __restrict__ qbF,
                                               u16* __restrict__ qTF,
                                               float* __restrict__ qw) {
  const int ch = blockIdx.x, bb = blockIdx.y, t = threadIdx.x;
  if (ch == 6) {   // qw[b,j] = q[b,j,:].w_q + b_q + b_cq  (4 threads per j-row)
    int j = t >> 2, qt = t & 3;
    const float* qr = q + ((size_t)bb * QL + j) * H;
    float s = 0.f;
#pragma unroll 8
    for (int p = 0; p < 48; ++p) {
      float4 v = *(const float4*)(qr + (qt * 48 + p) * 4);
      float4 w = *(const float4*)(w_q + (qt * 48 + p) * 4);
      s += v.x * w.x + v.y * w.y + v.z * w.z + v.w * w.w;
    }
    s += __shfl_xor(s, 1);
    s += __shfl_xor(s, 2);
    if (qt == 0) qw[bb * QL + j] = s + b_q[0] + b_cq[0];
    return;
  }
  __shared__ u16 tR[64 * 132], tS[64 * 132];
  const int d0 = ch * 128;
#pragma unroll
  for (int s2 = 0; s2 < 8; ++s2) {
    int idx = t + s2 * 256, j = idx >> 5, d4 = idx & 31;
    size_t go = ((size_t)(bb * QL + j)) * H + d0 + d4 * 4;
    float4 v = *(const float4*)(q + go);
    float4 w = *(const float4*)(w_cq + d0 + d4 * 4);
    uint2 raw, scl;
    raw.x = f2b(v.x) | ((u32)f2b(v.y) << 16);
    raw.y = f2b(v.z) | ((u32)f2b(v.w) << 16);
    scl.x = f2b(v.x * w.x) | ((u32)f2b(v.y * w.y) << 16);
    scl.y = f2b(v.z * w.z) | ((u32)f2b(v.w * w.w) << 16);
    *(uint2*)&tR[j * 132 + d4 * 4] = raw;
    *(uint2*)&tS[j * 132 + d4 * 4] = scl;
  }
  __syncthreads();
  {  // qbF fragments: (jt = t>>6, kt local 0..3), lane l
    int l = t & 63, jt = t >> 6, lr = l & 15, lg = l >> 4;
#pragma unroll
    for (int kt = 0; kt < 4; ++kt) {
      u16 vals[8];
#pragma unroll
      for (int e = 0; e < 8; ++e)
        vals[e] = tS[(jt * 16 + lr) * 132 + kt * 32 + lg * 8 + e];
      uint4 pk;
      pk.x = vals[0] | ((u32)vals[1] << 16);
      pk.y = vals[2] | ((u32)vals[3] << 16);
      pk.z = vals[4] | ((u32)vals[5] << 16);
      pk.w = vals[6] | ((u32)vals[7] << 16);
      *(uint4*)(qbF + ((((size_t)bb * 4 + jt) * 24) + ch * 4 + kt) * 512 + l * 8) = pk;
    }
  }
  {  // qTF fragments: uu local 0..7, h 0..1
#pragma unroll
    for (int rep = 0; rep < 4; ++rep) {
      int idx = rep * 256 + t;
      int l = idx & 63, h = (idx >> 6) & 1, uul = idx >> 7;
      int lr = l & 15, lg = l >> 4;
      u16 vals[8];
#pragma unroll
      for (int e = 0; e < 8; ++e)
        vals[e] = tR[(h * 32 + lg * 8 + e) * 132 + uul * 16 + lr];
      uint4 pk;
      pk.x = vals[0] | ((u32)vals[1] << 16);
      pk.y = vals[2] | ((u32)vals[3] << 16);
      pk.z = vals[4] | ((u32)vals[5] << 16);
      pk.w = vals[6] | ((u32)vals[7] << 16);
      *(uint4*)(qTF + (((size_t)bb * 48 + ch * 8 + uul) * 2 + h) * 512 + l * 8) = pk;
    }
  }
}

// ---------------- main kernel ----------------
__global__ __launch_bounds__(256, 2) void ka(const float* __restrict__ c,
                                             const float* __restrict__ c_mask,
                                             const float* __restrict__ q_mask,
                                             const float* __restrict__ w_c,
                                             const float* __restrict__ b_c,
                                             const float* __restrict__ qw,
                                             const u16* __restrict__ qbF,
                                             const u16* __restrict__ qTF,
                                             float* __restrict__ rowmax,
                                             float* __restrict__ out) {
  __shared__ __align__(16) char shm[8 * OSTR * 4];  // 24.7 KB: cA bf16 / oS f32 union
  __shared__ float sS[IT * 68];
  __shared__ u16 aS[IT * 64];
  float* oS = (float*)shm;

  const int t = threadIdx.x, lane = t & 63;
  const int wid = __builtin_amdgcn_readfirstlane(t >> 6);
  const int bb = blockIdx.y, i0 = blockIdx.x * IT;
  const int lr = lane & 15, lg = lane >> 4;
  const int sw = (lr & 7) << 4;

  // ---- stage c tile (16x768) -> bf16 swizzled LDS, fused cw = c.w_c
  float cwq = 0.f;
  {
    int row = t >> 4, c4b = t & 15;
    size_t cb0 = ((size_t)bb * CL + i0 + row) * H;
#pragma unroll
    for (int u = 0; u < 12; ++u) {
      int col4 = c4b + u * 16;
      float4 v = *(const float4*)(c + cb0 + col4 * 4);
      float4 w = *(const float4*)(w_c + col4 * 4);
      cwq += v.x * w.x + v.y * w.y + v.z * w.z + v.w * w.w;
      uint2 pk;
      pk.x = f2b(v.x) | ((u32)f2b(v.y) << 16);
      pk.y = f2b(v.z) | ((u32)f2b(v.w) << 16);
      int byte = row * 1536 + ((col4 * 8) ^ ((row & 7) << 4));
      *(uint2*)(shm + byte) = pk;
    }
    cwq += __shfl_xor(cwq, 1);
    cwq += __shfl_xor(cwq, 2);
    cwq += __shfl_xor(cwq, 4);
    cwq += __shfl_xor(cwq, 8);   // all 16 lanes of quarter g hold cw(row 4*wid+g)
  }
  const float qw_r = qw[bb * QL + lane];   // includes b_q + b_cq
  const float qm_r = q_mask[bb * QL + lane];
  const float bc = b_c[0];
  __syncthreads();

  // ---- phase 1: s' = c @ (q*w_cq)^T   (B from fragment-major qbF, coalesced)
  f32x4 acc0 = {0.f, 0.f, 0.f, 0.f}, acc1 = {0.f, 0.f, 0.f, 0.f};
  {
    const u16* qbp = qbF + (((size_t)bb * 4 + wid) * 24) * 512 + lane * 8;
    const char* ap = shm + lr * 1536;
#pragma unroll
    for (int kt = 0; kt < 24; kt += 2) {
      bfx8 av0 = *(const bfx8*)(ap + ((kt * 64 + lg * 16) ^ sw));
      bfx8 av1 = *(const bfx8*)(ap + (((kt + 1) * 64 + lg * 16) ^ sw));
      bfx8 bv0 = *(const bfx8*)(qbp + kt * 512);
      bfx8 bv1 = *(const bfx8*)(qbp + (kt + 1) * 512);
      acc0 = __builtin_amdgcn_mfma_f32_16x16x32_bf16(av0, bv0, acc0, 0, 0, 0);
      acc1 = __builtin_amdgcn_mfma_f32_16x16x32_bf16(av1, bv1, acc1, 0, 0, 0);
    }
  }
#pragma unroll
  for (int m = 0; m < 4; ++m)
    sS[(lg * 4 + m) * 68 + wid * 16 + lr] = acc0[m] + acc1[m];
  __syncthreads();

  // ---- phase 2: softmax over j (lane = j), rowmax, a -> bf16 LDS
#pragma unroll
  for (int rr = 0; rr < 4; ++rr) {
    int r = wid * 4 + rr;
    float s = sS[r * 68 + lane] + qw_r;
    float mraw = wredmax(s);
    float sm = (qm_r > 0.5f) ? s : NEGV;
    float mm = wredmax(sm);
    float p = __expf(sm - mm);
    float ps = wredsum(p);
    float a = p / ps;
    float cwr = __shfl(cwq, rr * 16);
    if (lane == 0) {
      float cmv = c_mask[bb * CL + i0 + r];
      rowmax[bb * CL + i0 + r] = (cmv > 0.5f) ? (mraw + cwr + bc) : NEGV;
    }
    int byte = r * 128 + ((lane * 2) ^ ((r & 7) << 4));
    *(u16*)((char*)aS + byte) = f2b(a);
  }
  __syncthreads();

  // ---- phase 3: c2q = a @ q  (B from fragment-major qTF, coalesced)
  bfx8 a0 = *(const bfx8*)((char*)aS + lr * 128 + ((lg * 16) ^ sw));
  bfx8 a1 = *(const bfx8*)((char*)aS + lr * 128 + ((64 + lg * 16) ^ sw));
  const u16* qtp = qTF + (size_t)bb * 49152 + lane * 8;
  f32x4 o[12];
#pragma unroll
  for (int u = 0; u < 12; ++u) {
    int uu = wid * 12 + u;
    bfx8 b0 = *(const bfx8*)(qtp + (size_t)uu * 1024);
    bfx8 b1 = *(const bfx8*)(qtp + (size_t)uu * 1024 + 512);
    f32x4 v = {0.f, 0.f, 0.f, 0.f};
    v = __builtin_amdgcn_mfma_f32_16x16x32_bf16(a0, b0, v, 0, 0, 0);
    v = __builtin_amdgcn_mfma_f32_16x16x32_bf16(a1, b1, v, 0, 0, 0);
    o[u] = v;
  }

  // ---- two-pass epilogue through oS (8 rows at a time), coalesced f4 stores
#pragma unroll
  for (int p = 0; p < 2; ++p) {
    if (p) __syncthreads();
#pragma unroll
    for (int u = 0; u < 12; ++u) {
      int d = wid * 192 + u * 16 + lr;
      oS[(lg * 2 + 0) * OSTR + d] = o[u][2 * p];
      oS[(lg * 2 + 1) * OSTR + d] = o[u][2 * p + 1];
    }
    __syncthreads();
    int row8 = t >> 5, c32 = t & 31;
    int g = row8 >> 1, mo = row8 & 1;
    int ri = g * 4 + 2 * p + mo;
    size_t grow = (size_t)bb * CL + i0 + ri;
    const float* crow = c + grow * H;
    float* ob = out + grow * OD;
#pragma unroll
    for (int k = 0; k < 6; ++k) {
      int d = (c32 + k * 32) * 4;
      float4 cv = *(const float4*)(crow + d);
      float4 ov = *(const float4*)&oS[row8 * OSTR + d];
      *(float4*)(ob + d) = cv;
      *(float4*)(ob + H + d) = ov;
      *(float4*)(ob + 2 * H + d) = make_float4(cv.x * ov.x, cv.y * ov.y,
                                               cv.z * ov.z, cv.w * ov.w);
    }
  }
}

// ---------------- fused b_att softmax + q2c partials ----------------
__global__ __launch_bounds__(256) void kb(const float* __restrict__ rowmax,
                                          const float* __restrict__ c,
                                          float* __restrict__ part) {
  int s = blockIdx.x, b = blockIdx.y, t = threadIdx.x;
  __shared__ float red[8];
  __shared__ float ba[16];
  float v0 = rowmax[b * CL + t], v1 = rowmax[b * CL + t + 256];
  float m = wredmax(fmaxf(v0, v1));
  if ((t & 63) == 0) red[t >> 6] = m;
  __syncthreads();
  m = fmaxf(fmaxf(red[0], red[1]), fmaxf(red[2], red[3]));
  float p = __expf(v0 - m) + __expf(v1 - m);
  p = wredsum(p);
  if ((t & 63) == 0) red[4 + (t >> 6)] = p;
  __syncthreads();
  float ssum = red[4] + red[5] + red[6] + red[7];
  if (t < 16) ba[t] = __expf(rowmax[b * CL + s * 16 + t] - m) / ssum;
  __syncthreads();
  if (t < 192) {
    const float* cb = c + ((size_t)b * CL + s * 16) * H;
    float4 acc = make_float4(0.f, 0.f, 0.f, 0.f);
#pragma unroll
    for (int r = 0; r < 16; ++r) {
      float w = ba[r];
      float4 cv = *(const float4*)(cb + (size_t)r * H + t * 4);
      acc.x += w * cv.x; acc.y += w * cv.y; acc.z += w * cv.z; acc.w += w * cv.w;
    }
    *(float4*)(part + ((size_t)b * 32 + s) * H + t * 4) = acc;
  }
}

// ---------------- q2c reduce ----------------
__global__ __launch_bounds__(256) void kb3(const float* __restrict__ part,
                                           float* __restrict__ q2c) {
  int b = blockIdx.x / 3, third = blockIdx.x % 3, t = threadIdx.x;
  int d = third * 256 + t;
  float s = 0.f;
  for (int k = 0; k < 32; ++k) s += part[((size_t)b * 32 + k) * H + d];
  q2c[b * H + d] = s;
}

// ---------------- out seg3 = c * q2c ----------------
__global__ __launch_bounds__(256) void kc(const float* __restrict__ c,
                                          const float* __restrict__ q2c,
                                          float* __restrict__ out) {
  const float4* c4 = (const float4*)c;
  const float4* g4 = (const float4*)q2c;
  float4* o4 = (float4*)out;
  int idx = blockIdx.x * 256 + threadIdx.x;
#pragma unroll
  for (int k = 0; k < 3; ++k, idx += 2048 * 256) {
    int row = idx / 192, dq = idx - row * 192;
    int b = row >> 9;
    float4 cv = c4[(size_t)row * 192 + dq];
    float4 gv = g4[b * 192 + dq];
    float4 r;
    r.x = cv.x * gv.x; r.y = cv.y * gv.y; r.z = cv.z * gv.z; r.w = cv.w * gv.w;
    o4[(size_t)row * 768 + 576 + dq] = r;
  }
}

extern "C" void kernel_launch(void* const* d_in, const int* in_sizes, int n_in,
                              void* d_out, int out_size, void* d_ws, size_t ws_size,
                              hipStream_t stream) {
  const float* c      = (const float*)d_in[0];
  const float* q      = (const float*)d_in[1];
  const float* c_mask = (const float*)d_in[2];
  const float* q_mask = (const float*)d_in[3];
  const float* w_c    = (const float*)d_in[4];
  const float* b_c    = (const float*)d_in[5];
  const float* w_q    = (const float*)d_in[6];
  const float* b_q    = (const float*)d_in[7];
  const float* w_cq   = (const float*)d_in[8];
  const float* b_cq   = (const float*)d_in[9];
  float* out = (float*)d_out;
  float* ws  = (float*)d_ws;
  float* qw     = ws + WS_QW;
  float* rowmax = ws + WS_ROWMAX;
  float* part   = ws + WS_PART;
  float* q2c    = ws + WS_Q2C;
  u16*   qbF    = (u16*)(ws + WS_QBF);
  u16*   qTF    = (u16*)(ws + WS_QTF);

  k_qprep<<<dim3(7, B_), 256, 0, stream>>>(q, w_cq, w_q, b_q, b_cq, qbF, qTF, qw);
  ka<<<dim3(CL / IT, B_), 256, 0, stream>>>(c, c_mask, q_mask, w_c, b_c,
                                            qw, qbF, qTF, rowmax, out);
  kb<<<dim3(32, B_), 256, 0, stream>>>(rowmax, c, part);
  kb3<<<B_ * 3, 256, 0, stream>>>(part, q2c);
  kc<<<2048, 256, 0, stream>>>(c, q2c, out);
}

// Round 6
// 58.263 us; speedup vs baseline: 2.1675x; 1.0492x over previous
//
#include <hip/hip_runtime.h>
#include <math.h>
#include <stdint.h>

#define NEGV -1e30f
typedef unsigned short u16;
typedef unsigned int u32;
typedef short bfx8 __attribute__((ext_vector_type(8)));
typedef float f32x4 __attribute__((ext_vector_type(4)));

constexpr int B_  = 16;
constexpr int CL  = 512;
constexpr int QL  = 64;
constexpr int H   = 768;
constexpr int OD  = 4 * H;     // 3072 output cols
constexpr int IT  = 16;        // i-rows per block in ka
constexpr int OSTR = 772;      // oS row stride in f32

// ws layout (float offsets)
constexpr size_t WS_QW     = 0;            // [1024]  qw[b,j] (incl b_q + b_cq)
constexpr size_t WS_ROWMAX = 1024;         // [8192]
constexpr size_t WS_PART   = 17408;        // [16*32*768]
constexpr size_t WS_QBF    = 422912;       // u16[16][4][24][64][8]  frag-major bf16(q*w_cq)
constexpr size_t WS_QTF    = 816128;       // u16[16][48][2][64][8]  frag-major bf16(q)^T

__device__ __forceinline__ u16 f2b(float x) {     // fp32 -> bf16 RTNE
  u32 u = __float_as_uint(x);
  u += 0x7FFFu + ((u >> 16) & 1u);
  return (u16)(u >> 16);
}
__device__ __forceinline__ float wredmax(float v) {
#pragma unroll
  for (int off = 32; off; off >>= 1) v = fmaxf(v, __shfl_xor(v, off));
  return v;
}
__device__ __forceinline__ float wredsum(float v) {
#pragma unroll
  for (int off = 32; off; off >>= 1) v += __shfl_xor(v, off);
  return v;
}

// ---------------- prologue: qw + fragment-major qbF/qTF ----------------
__global__ __launch_bounds__(256) void k_qprep(const float* __restrict__ q,
                                               const float* __restrict__ w_cq,
                                               const float* __restrict__ w_q,
                                               const float* __restrict__ b_q,
                                               const float* __restrict__ b_cq,
                                               u16* __restrict__ qbF,
                                               u16* __restrict__ qTF,
                                               float* __restrict__ qw) {
  const int ch = blockIdx.x, bb = blockIdx.y, t = threadIdx.x;
  if (ch == 6) {   // qw[b,j] = q[b,j,:].w_q + b_q + b_cq  (4 threads per j-row)
    int j = t >> 2, qt = t & 3;
    const float* qr = q + ((size_t)bb * QL + j) * H;
    float s = 0.f;
#pragma unroll 8
    for (int p = 0; p < 48; ++p) {
      float4 v = *(const float4*)(qr + (qt * 48 + p) * 4);
      float4 w = *(const float4*)(w_q + (qt * 48 + p) * 4);
      s += v.x * w.x + v.y * w.y + v.z * w.z + v.w * w.w;
    }
    s += __shfl_xor(s, 1);
    s += __shfl_xor(s, 2);
    if (qt == 0) qw[bb * QL + j] = s + b_q[0] + b_cq[0];
    return;
  }
  __shared__ u16 tR[64 * 132], tS[64 * 132];
  const int d0 = ch * 128;
#pragma unroll
  for (int s2 = 0; s2 < 8; ++s2) {
    int idx = t + s2 * 256, j = idx >> 5, d4 = idx & 31;
    size_t go = ((size_t)(bb * QL + j)) * H + d0 + d4 * 4;
    float4 v = *(const float4*)(q + go);
    float4 w = *(const float4*)(w_cq + d0 + d4 * 4);
    uint2 raw, scl;
    raw.x = f2b(v.x) | ((u32)f2b(v.y) << 16);
    raw.y = f2b(v.z) | ((u32)f2b(v.w) << 16);
    scl.x = f2b(v.x * w.x) | ((u32)f2b(v.y * w.y) << 16);
    scl.y = f2b(v.z * w.z) | ((u32)f2b(v.w * w.w) << 16);
    *(uint2*)&tR[j * 132 + d4 * 4] = raw;
    *(uint2*)&tS[j * 132 + d4 * 4] = scl;
  }
  __syncthreads();
  {  // qbF fragments
    int l = t & 63, jt = t >> 6, lr = l & 15, lg = l >> 4;
#pragma unroll
    for (int kt = 0; kt < 4; ++kt) {
      u16 vals[8];
#pragma unroll
      for (int e = 0; e < 8; ++e)
        vals[e] = tS[(jt * 16 + lr) * 132 + kt * 32 + lg * 8 + e];
      uint4 pk;
      pk.x = vals[0] | ((u32)vals[1] << 16);
      pk.y = vals[2] | ((u32)vals[3] << 16);
      pk.z = vals[4] | ((u32)vals[5] << 16);
      pk.w = vals[6] | ((u32)vals[7] << 16);
      *(uint4*)(qbF + ((((size_t)bb * 4 + jt) * 24) + ch * 4 + kt) * 512 + l * 8) = pk;
    }
  }
  {  // qTF fragments
#pragma unroll
    for (int rep = 0; rep < 4; ++rep) {
      int idx = rep * 256 + t;
      int l = idx & 63, h = (idx >> 6) & 1, uul = idx >> 7;
      int lr = l & 15, lg = l >> 4;
      u16 vals[8];
#pragma unroll
      for (int e = 0; e < 8; ++e)
        vals[e] = tR[(h * 32 + lg * 8 + e) * 132 + uul * 16 + lr];
      uint4 pk;
      pk.x = vals[0] | ((u32)vals[1] << 16);
      pk.y = vals[2] | ((u32)vals[3] << 16);
      pk.z = vals[4] | ((u32)vals[5] << 16);
      pk.w = vals[6] | ((u32)vals[7] << 16);
      *(uint4*)(qTF + (((size_t)bb * 48 + ch * 8 + uul) * 2 + h) * 512 + l * 8) = pk;
    }
  }
}

// ---------------- main kernel ----------------
__global__ __launch_bounds__(256, 2) void ka(const float* __restrict__ c,
                                             const float* __restrict__ c_mask,
                                             const float* __restrict__ q_mask,
                                             const float* __restrict__ w_c,
                                             const float* __restrict__ b_c,
                                             const float* __restrict__ qw,
                                             const u16* __restrict__ qbF,
                                             const u16* __restrict__ qTF,
                                             float* __restrict__ rowmax,
                                             float* __restrict__ out) {
  __shared__ __align__(16) char shm[IT * OSTR * 4];  // 49.4 KB: cA bf16 / oS f32 union
  __shared__ float sS[IT * 68];
  __shared__ u16 aS[IT * 64];
  float* oS = (float*)shm;

  const int t = threadIdx.x, lane = t & 63;
  const int wid = __builtin_amdgcn_readfirstlane(t >> 6);
  const int bb = blockIdx.y, i0 = blockIdx.x * IT;
  const int lr = lane & 15, lg = lane >> 4;
  const int sw = (lr & 7) << 4;

  const u16* qbp = qbF + (((size_t)bb * 4 + wid) * 24) * 512 + lane * 8;
  const u16* qtp = qTF + (size_t)bb * 49152 + lane * 8;

  // early-issue phase-1 B prefetch (independent of LDS staging)
  bfx8 qpf0 = *(const bfx8*)(qbp);
  bfx8 qpf1 = *(const bfx8*)(qbp + 512);

  // ---- stage c tile (16x768) -> bf16 swizzled LDS, fused cw = c.w_c
  float cwq = 0.f;
  {
    int row = t >> 4, c4b = t & 15;
    size_t cb0 = ((size_t)bb * CL + i0 + row) * H;
#pragma unroll
    for (int u = 0; u < 12; ++u) {
      int col4 = c4b + u * 16;
      float4 v = *(const float4*)(c + cb0 + col4 * 4);
      float4 w = *(const float4*)(w_c + col4 * 4);
      cwq += v.x * w.x + v.y * w.y + v.z * w.z + v.w * w.w;
      uint2 pk;
      pk.x = f2b(v.x) | ((u32)f2b(v.y) << 16);
      pk.y = f2b(v.z) | ((u32)f2b(v.w) << 16);
      int byte = row * 1536 + ((col4 * 8) ^ ((row & 7) << 4));
      *(uint2*)(shm + byte) = pk;
    }
    cwq += __shfl_xor(cwq, 1);
    cwq += __shfl_xor(cwq, 2);
    cwq += __shfl_xor(cwq, 4);
    cwq += __shfl_xor(cwq, 8);   // 16 lanes of quarter g hold cw(row 4*wid+g)
  }
  const float qw_r = qw[bb * QL + lane];   // includes b_q + b_cq
  const float qm_r = q_mask[bb * QL + lane];
  const float bc = b_c[0];
  __syncthreads();

  // ---- phase 1: s' = c @ (q*w_cq)^T
  f32x4 acc0 = {0.f, 0.f, 0.f, 0.f}, acc1 = {0.f, 0.f, 0.f, 0.f};
  {
    const char* ap = shm + lr * 1536;
    acc0 = __builtin_amdgcn_mfma_f32_16x16x32_bf16(
        *(const bfx8*)(ap + ((lg * 16) ^ sw)), qpf0, acc0, 0, 0, 0);
    acc1 = __builtin_amdgcn_mfma_f32_16x16x32_bf16(
        *(const bfx8*)(ap + ((64 + lg * 16) ^ sw)), qpf1, acc1, 0, 0, 0);
#pragma unroll
    for (int kt = 2; kt < 24; kt += 2) {
      bfx8 av0 = *(const bfx8*)(ap + ((kt * 64 + lg * 16) ^ sw));
      bfx8 av1 = *(const bfx8*)(ap + (((kt + 1) * 64 + lg * 16) ^ sw));
      bfx8 bv0 = *(const bfx8*)(qbp + kt * 512);
      bfx8 bv1 = *(const bfx8*)(qbp + (kt + 1) * 512);
      acc0 = __builtin_amdgcn_mfma_f32_16x16x32_bf16(av0, bv0, acc0, 0, 0, 0);
      acc1 = __builtin_amdgcn_mfma_f32_16x16x32_bf16(av1, bv1, acc1, 0, 0, 0);
    }
  }
  // prefetch first phase-3 B fragments before the softmax barriers
  bfx8 pf0 = *(const bfx8*)(qtp + (size_t)(wid * 12 + 0) * 1024);
  bfx8 pf1 = *(const bfx8*)(qtp + (size_t)(wid * 12 + 0) * 1024 + 512);
  bfx8 pf2 = *(const bfx8*)(qtp + (size_t)(wid * 12 + 1) * 1024);
  bfx8 pf3 = *(const bfx8*)(qtp + (size_t)(wid * 12 + 1) * 1024 + 512);
#pragma unroll
  for (int m = 0; m < 4; ++m)
    sS[(lg * 4 + m) * 68 + wid * 16 + lr] = acc0[m] + acc1[m];
  __syncthreads();

  // ---- phase 2: softmax over j (lane = j), rowmax, a -> bf16 LDS
#pragma unroll
  for (int rr = 0; rr < 4; ++rr) {
    int r = wid * 4 + rr;
    float s = sS[r * 68 + lane] + qw_r;
    float mraw = wredmax(s);
    float sm = (qm_r > 0.5f) ? s : NEGV;
    float mm = wredmax(sm);
    float p = __expf(sm - mm);
    float ps = wredsum(p);
    float a = p / ps;
    float cwr = __shfl(cwq, rr * 16);
    if (lane == 0) {
      float cmv = c_mask[bb * CL + i0 + r];
      rowmax[bb * CL + i0 + r] = (cmv > 0.5f) ? (mraw + cwr + bc) : NEGV;
    }
    int byte = r * 128 + ((lane * 2) ^ ((r & 7) << 4));
    *(u16*)((char*)aS + byte) = f2b(a);
  }
  __syncthreads();

  // ---- phase 3: c2q = a @ q
  bfx8 a0 = *(const bfx8*)((char*)aS + lr * 128 + ((lg * 16) ^ sw));
  bfx8 a1 = *(const bfx8*)((char*)aS + lr * 128 + ((64 + lg * 16) ^ sw));
  f32x4 o[12];
  {
    f32x4 v0 = {0.f, 0.f, 0.f, 0.f};
    v0 = __builtin_amdgcn_mfma_f32_16x16x32_bf16(a0, pf0, v0, 0, 0, 0);
    v0 = __builtin_amdgcn_mfma_f32_16x16x32_bf16(a1, pf1, v0, 0, 0, 0);
    o[0] = v0;
    f32x4 v1 = {0.f, 0.f, 0.f, 0.f};
    v1 = __builtin_amdgcn_mfma_f32_16x16x32_bf16(a0, pf2, v1, 0, 0, 0);
    v1 = __builtin_amdgcn_mfma_f32_16x16x32_bf16(a1, pf3, v1, 0, 0, 0);
    o[1] = v1;
  }
#pragma unroll
  for (int u = 2; u < 12; ++u) {
    int uu = wid * 12 + u;
    bfx8 b0 = *(const bfx8*)(qtp + (size_t)uu * 1024);
    bfx8 b1 = *(const bfx8*)(qtp + (size_t)uu * 1024 + 512);
    f32x4 v = {0.f, 0.f, 0.f, 0.f};
    v = __builtin_amdgcn_mfma_f32_16x16x32_bf16(a0, b0, v, 0, 0, 0);
    v = __builtin_amdgcn_mfma_f32_16x16x32_bf16(a1, b1, v, 0, 0, 0);
    o[u] = v;
  }

  // ---- single-pass epilogue via oS (phase-1 done by earlier barrier; cA dead)
#pragma unroll
  for (int u = 0; u < 12; ++u) {
    int d = wid * 192 + u * 16 + lr;
#pragma unroll
    for (int m = 0; m < 4; ++m)
      oS[(lg * 4 + m) * OSTR + d] = o[u][m];
  }
  __syncthreads();
  {
    int row = t >> 4, c4b = t & 15;
    size_t grow = (size_t)bb * CL + i0 + row;
    const float* crow = c + grow * H;
    float* ob = out + grow * OD;
#pragma unroll
    for (int k = 0; k < 12; ++k) {
      int d = (c4b + k * 16) * 4;
      float4 cv = *(const float4*)(crow + d);
      float4 ov = *(const float4*)&oS[row * OSTR + d];
      *(float4*)(ob + d) = cv;
      *(float4*)(ob + H + d) = ov;
      *(float4*)(ob + 2 * H + d) = make_float4(cv.x * ov.x, cv.y * ov.y,
                                               cv.z * ov.z, cv.w * ov.w);
    }
  }
}

// ---------------- fused b_att softmax + q2c partials ----------------
__global__ __launch_bounds__(256) void kb(const float* __restrict__ rowmax,
                                          const float* __restrict__ c,
                                          float* __restrict__ part) {
  int s = blockIdx.x, b = blockIdx.y, t = threadIdx.x;
  __shared__ float red[8];
  __shared__ float ba[16];
  float v0 = rowmax[b * CL + t], v1 = rowmax[b * CL + t + 256];
  float m = wredmax(fmaxf(v0, v1));
  if ((t & 63) == 0) red[t >> 6] = m;
  __syncthreads();
  m = fmaxf(fmaxf(red[0], red[1]), fmaxf(red[2], red[3]));
  float p = __expf(v0 - m) + __expf(v1 - m);
  p = wredsum(p);
  if ((t & 63) == 0) red[4 + (t >> 6)] = p;
  __syncthreads();
  float ssum = red[4] + red[5] + red[6] + red[7];
  if (t < 16) ba[t] = __expf(rowmax[b * CL + s * 16 + t] - m) / ssum;
  __syncthreads();
  if (t < 192) {
    const float* cb = c + ((size_t)b * CL + s * 16) * H;
    float4 acc = make_float4(0.f, 0.f, 0.f, 0.f);
#pragma unroll
    for (int r = 0; r < 16; ++r) {
      float w = ba[r];
      float4 cv = *(const float4*)(cb + (size_t)r * H + t * 4);
      acc.x += w * cv.x; acc.y += w * cv.y; acc.z += w * cv.z; acc.w += w * cv.w;
    }
    *(float4*)(part + ((size_t)b * 32 + s) * H + t * 4) = acc;
  }
}

// ---------------- seg3: per-strip q2c reduce + c*q2c write ----------------
__global__ __launch_bounds__(256) void kc2(const float* __restrict__ part,
                                           const float* __restrict__ c,
                                           float* __restrict__ out) {
  __shared__ float4 redS[8][32];
  __shared__ float4 q2cS[32];
  const int b = blockIdx.y;
  const int s = blockIdx.x >> 4, rg = blockIdx.x & 15;
  const int t = threadIdx.x;
  const int grp = t >> 5, col4 = t & 31;
  float4 acc = make_float4(0.f, 0.f, 0.f, 0.f);
#pragma unroll
  for (int u = 0; u < 4; ++u) {
    float4 v = *(const float4*)(part + ((size_t)b * 32 + grp * 4 + u) * H +
                                s * 128 + col4 * 4);
    acc.x += v.x; acc.y += v.y; acc.z += v.z; acc.w += v.w;
  }
  redS[grp][col4] = acc;
  __syncthreads();
  if (t < 32) {
    float4 sum = redS[0][t];
#pragma unroll
    for (int g = 1; g < 8; ++g) {
      float4 v = redS[g][t];
      sum.x += v.x; sum.y += v.y; sum.z += v.z; sum.w += v.w;
    }
    q2cS[t] = sum;
  }
  __syncthreads();
  float4 gv = q2cS[col4];
  const int sub = t >> 5;
#pragma unroll
  for (int r2 = 0; r2 < 4; ++r2) {
    int row = rg * 32 + sub * 4 + r2;
    size_t grow = (size_t)b * CL + row;
    float4 cv = *(const float4*)(c + grow * H + s * 128 + col4 * 4);
    *(float4*)(out + grow * OD + 3 * H + s * 128 + col4 * 4) =
        make_float4(cv.x * gv.x, cv.y * gv.y, cv.z * gv.z, cv.w * gv.w);
  }
}

extern "C" void kernel_launch(void* const* d_in, const int* in_sizes, int n_in,
                              void* d_out, int out_size, void* d_ws, size_t ws_size,
                              hipStream_t stream) {
  const float* c      = (const float*)d_in[0];
  const float* q      = (const float*)d_in[1];
  const float* c_mask = (const float*)d_in[2];
  const float* q_mask = (const float*)d_in[3];
  const float* w_c    = (const float*)d_in[4];
  const float* b_c    = (const float*)d_in[5];
  const float* w_q    = (const float*)d_in[6];
  const float* b_q    = (const float*)d_in[7];
  const float* w_cq   = (const float*)d_in[8];
  const float* b_cq   = (const float*)d_in[9];
  float* out = (float*)d_out;
  float* ws  = (float*)d_ws;
  float* qw     = ws + WS_QW;
  float* rowmax = ws + WS_ROWMAX;
  float* part   = ws + WS_PART;
  u16*   qbF    = (u16*)(ws + WS_QBF);
  u16*   qTF    = (u16*)(ws + WS_QTF);

  k_qprep<<<dim3(7, B_), 256, 0, stream>>>(q, w_cq, w_q, b_q, b_cq, qbF, qTF, qw);
  ka<<<dim3(CL / IT, B_), 256, 0, stream>>>(c, c_mask, q_mask, w_c, b_c,
                                            qw, qbF, qTF, rowmax, out);
  kb<<<dim3(32, B_), 256, 0, stream>>>(rowmax, c, part);
  kc2<<<dim3(96, B_), 256, 0, stream>>>(part, c, out);
}